// Round 1
// baseline (180.973 us; speedup 1.0000x reference)
//
#include <hip/hip_runtime.h>
#include <stdint.h>

// ---------------------------------------------------------------------------
// CrossAttention_43061342110469 — algebraic reduction:
// einsum('bvhd,bhqk->bvhd', v, softmax(scores)) == v * L  (softmax rows sum
// to 1; summed over q gives L=2048). So out = 2048*(x @ Wv @ Wo) + const.
// encoder_x / Wq / bq / Wk / bk do not affect the output.
//
// 3 kernels: prep (cast_x + transpose_cast(Wo) + bias_fuse, block-range
// dispatch — all independent), gemm_w (Wt = 2048*(Wv@Wo)^T, 32x64 tiles so
// 512 blocks = 2/CU to overlap barrier drains), gemm_main (bf16 MFMA,
// 128x64 tiles, XCD-aware order, XOR-swizzled LDS, coalesced epilogue).
// ---------------------------------------------------------------------------

typedef __attribute__((ext_vector_type(8))) short bf16x8;
typedef __attribute__((ext_vector_type(4))) float f32x4;

typedef __attribute__((address_space(1))) void as1_void;
typedef __attribute__((address_space(3))) void as3_void;
#define GLD16(g, s)                                                          \
  __builtin_amdgcn_global_load_lds((as1_void*)(g), (as3_void*)(s), 16, 0, 0)

__device__ __forceinline__ short f2bf(float f) {
  union { float f; uint32_t u; } v; v.f = f;
  uint32_t r = v.u + 0x7FFFu + ((v.u >> 16) & 1u);  // round-to-nearest-even
  return (short)(r >> 16);
}

// pack 8 fp32 -> bf16x8, round-half-up (+0x8000, take high16 via v_perm)
__device__ __forceinline__ bf16x8 pack8(f32x4 a, f32x4 b) {
  union { f32x4 f; uint32_t u[4]; } x, y;
  x.f = a; y.f = b;
#pragma unroll
  for (int t = 0; t < 4; ++t) x.u[t] += 0x8000u;
#pragma unroll
  for (int t = 0; t < 4; ++t) y.u[t] += 0x8000u;
  union { bf16x8 v; uint32_t u[4]; } o;
  o.u[0] = __builtin_amdgcn_perm(x.u[1], x.u[0], 0x07060302);
  o.u[1] = __builtin_amdgcn_perm(x.u[3], x.u[2], 0x07060302);
  o.u[2] = __builtin_amdgcn_perm(y.u[1], y.u[0], 0x07060302);
  o.u[3] = __builtin_amdgcn_perm(y.u[3], y.u[2], 0x07060302);
  return o.v;
}

// ---- prep: blocks [0,4096) cast x; [4096,4352) transpose Wo; [4352,4416)
// fused bias. All three independent; branch is block-uniform. ---------------
__global__ __launch_bounds__(256) void prep(
    const float* __restrict__ x, short* __restrict__ x_bf,
    const float* __restrict__ Wo, short* __restrict__ wot,
    const float* __restrict__ bv, const float* __restrict__ bo,
    float* __restrict__ biasc) {
  constexpr int N = 1024, D = 1024;
  __shared__ union {
    float tile[64][65];
    float red[256];
  } sm;
  const int b = blockIdx.x, tid = threadIdx.x;

  if (b < 4096) {  // ---- cast x: fp32 -> bf16, 8 elems/thread
    const int i = b * 256 + tid;
    const float4* p = (const float4*)x;
    float4 a = p[2 * (size_t)i], c = p[2 * (size_t)i + 1];
    bf16x8 o;
    o[0] = f2bf(a.x); o[1] = f2bf(a.y); o[2] = f2bf(a.z); o[3] = f2bf(a.w);
    o[4] = f2bf(c.x); o[5] = f2bf(c.y); o[6] = f2bf(c.z); o[7] = f2bf(c.w);
    *(bf16x8*)(x_bf + 8 * (size_t)i) = o;
  } else if (b < 4352) {  // ---- transpose-cast Wo (64x64 tiles via LDS)
    const int b2 = b - 4096;
    const int br = (b2 >> 4) * 64, bc = (b2 & 15) * 64;
#pragma unroll
    for (int t = 0; t < 16; ++t) {
      int idx = t * 256 + tid;
      int r = idx >> 6, c = idx & 63;
      sm.tile[r][c] = Wo[(size_t)(br + r) * N + bc + c];
    }
    __syncthreads();
#pragma unroll
    for (int t = 0; t < 16; ++t) {
      int idx = t * 256 + tid;
      int r = idx >> 6, c = idx & 63;
      wot[(size_t)(bc + r) * N + br + c] = f2bf(sm.tile[c][r]);
    }
  } else {  // ---- bias_c[n] = 2048 * sum_k bv[k]*Wo[k,n] + bo[n]
    const int b3 = b - 4352;
    const int nx = tid & 15, ky = tid >> 4;
    const int n = b3 * 16 + nx;
    float s = 0.f;
    for (int k = ky; k < D; k += 16)
      s += bv[k] * Wo[(size_t)k * N + n];
    sm.red[tid] = s;
    __syncthreads();
#pragma unroll
    for (int st = 128; st >= 16; st >>= 1) {
      if (tid < st) sm.red[tid] += sm.red[tid + st];
      __syncthreads();
    }
    if (ky == 0) biasc[n] = 2048.0f * sm.red[nx] + bo[n];
  }
}

// ---- Wt[m,k'] = 2048 * sum_j Wot[m,j] * Wv[k',j]; Wv staged as fp32 --------
// 32x64 tiles, BK=64, grid 16x32 = 512 blocks (2/CU so the per-tile barrier
// drains of co-resident blocks interleave — R6 had 256 blocks = 1/CU with
// latency fully exposed). 4 waves, each 16x32 (1x2 frags of 16x16x32).
__global__ __launch_bounds__(256) void gemm_w(
    const short* __restrict__ Wot, const float* __restrict__ Wv,
    short* __restrict__ Wt, int N, int K) {
  constexpr int BK = 64;
  __shared__ __align__(16) short As[32 * BK];   //  4 KB bf16
  __shared__ __align__(16) float Bsf[64 * BK];  // 16 KB fp32
  const int tid = threadIdx.x, lane = tid & 63, wave = tid >> 6;
  const int bm = blockIdx.y * 32, bn = blockIdx.x * 64;
  const int wm = (wave & 1) * 16, wn = (wave >> 1) * 32;
  const int l15 = lane & 15, quad = lane >> 4;

  f32x4 acc[2];
  acc[0] = (f32x4){0.f, 0.f, 0.f, 0.f};
  acc[1] = (f32x4){0.f, 0.f, 0.f, 0.f};

  // A: 32 rows x 8 chunks(16B) = 256 chunks, 1/thread, XOR swizzle
  const int ar = tid >> 3, ac8 = (tid & 7) ^ (ar & 7);
  const short* pa = Wot + (size_t)(bm + ar) * K + ac8 * 8;
  short* la = As + tid * 8;
  // B (fp32): 64 rows x 16 chunks(16B) = 1024 chunks, 4/thread
  const int br = tid >> 4, bc4 = (tid & 15) ^ (br & 7);
  const float* pb = Wv + (size_t)(bn + br) * K + bc4 * 4;
  float* lb = Bsf + tid * 4;

  for (int kt = 0; kt < K; kt += BK) {
    GLD16(pa, la);
#pragma unroll
    for (int s = 0; s < 4; ++s) GLD16(pb + (size_t)(16 * s) * K, lb + 1024 * s);
    pa += BK; pb += BK;
    __syncthreads();
#pragma unroll
    for (int kk = 0; kk < 2; ++kk) {
      const int r = wm + l15;
      bf16x8 af =
          *(const bf16x8*)(As + r * BK + ((kk * 4 + quad) ^ (r & 7)) * 8);
#pragma unroll
      for (int j = 0; j < 2; ++j) {
        const int rn = wn + j * 16 + l15;
        const int c4 = kk * 8 + quad * 2;
        f32x4 u0 = *(const f32x4*)(Bsf + (rn * 16 + (c4 ^ (rn & 7))) * 4);
        f32x4 u1 = *(const f32x4*)(Bsf + (rn * 16 + ((c4 + 1) ^ (rn & 7))) * 4);
        acc[j] = __builtin_amdgcn_mfma_f32_16x16x32_bf16(af, pack8(u0, u1),
                                                         acc[j], 0, 0, 0);
      }
    }
    __syncthreads();
  }
#pragma unroll
  for (int j = 0; j < 2; ++j) {
    const int col = bn + wn + j * 16 + l15;
    const int row0 = bm + wm + quad * 4;
#pragma unroll
    for (int r = 0; r < 4; ++r)
      Wt[(size_t)(row0 + r) * N + col] = f2bf(2048.f * acc[j][r]);
  }
}

// ---- out = x_bf @ Wt^T + bias; bf16 K-loop, 128x64 tile, XCD swizzle -------
// 1-D grid of 1024: bm = b&63 (b%8 = bm%8 -> all 16 N-tiles of one A-tile
// share an XCD's L2), bn = b>>6. ~4 blocks/CU hides K-loop barrier drains.
// Epilogue: acc -> LDS (stride-36) -> full-line dwordx4 stores.
__global__ __launch_bounds__(256) void gemm_main(
    const short* __restrict__ A, const short* __restrict__ Bt,
    const float* __restrict__ bias, float* __restrict__ Out,
    int M, int N, int K) {
  constexpr int BK = 64;
  __shared__ __align__(16) char smem[24576];  // As 16K + Bs 8K; epilogue T
  short* As = (short*)smem;
  short* Bs = (short*)(smem + 16384);
  const int tid = threadIdx.x, lane = tid & 63, wave = tid >> 6;
  const int b = blockIdx.x;
  const int bm = (b & 63) * 128;
  const int bn = (b >> 6) * 64;
  const int wm = (wave & 1) * 64, wn = (wave >> 1) * 32;
  const int l15 = lane & 15, quad = lane >> 4;

  f32x4 acc[4][2];
#pragma unroll
  for (int i = 0; i < 4; ++i)
#pragma unroll
    for (int j = 0; j < 2; ++j) acc[i][j] = (f32x4){0.f, 0.f, 0.f, 0.f};

  // staging with XOR chunk swizzle (LDS[row][c8] = global [row][c8^(row&7)])
  const int srow = tid >> 3, sc8 = (tid & 7) ^ (srow & 7);
  const short* pa = A + (size_t)(bm + srow) * K + sc8 * 8;
  const short* pb = Bt + (size_t)(bn + srow) * K + sc8 * 8;
  short* la = As + tid * 8;
  short* lb = Bs + tid * 8;

  for (int kt = 0; kt < K; kt += BK) {
#pragma unroll
    for (int s = 0; s < 4; ++s) GLD16(pa + (size_t)(32 * s) * K, la + 2048 * s);
#pragma unroll
    for (int s = 0; s < 2; ++s) GLD16(pb + (size_t)(32 * s) * K, lb + 2048 * s);
    pa += BK; pb += BK;
    __syncthreads();
#pragma unroll
    for (int kk = 0; kk < 2; ++kk) {
      bf16x8 af[4], bfr[2];
#pragma unroll
      for (int i = 0; i < 4; ++i) {
        const int r = wm + i * 16 + l15;
        af[i] = *(const bf16x8*)(As + r * BK + ((kk * 4 + quad) ^ (r & 7)) * 8);
      }
#pragma unroll
      for (int j = 0; j < 2; ++j) {
        const int r = wn + j * 16 + l15;
        bfr[j] = *(const bf16x8*)(Bs + r * BK + ((kk * 4 + quad) ^ (r & 7)) * 8);
      }
#pragma unroll
      for (int i = 0; i < 4; ++i)
#pragma unroll
        for (int j = 0; j < 2; ++j)
          acc[i][j] = __builtin_amdgcn_mfma_f32_16x16x32_bf16(
              af[i], bfr[j], acc[i][j], 0, 0, 0);
    }
    __syncthreads();
  }

  // epilogue: MFMA C layout (col=l15, row=quad*4+r) -> LDS stride-36 tile ->
  // full-line float4 stores. Per-wave T region; same-wave LDS ordering only.
  float* T = (float*)smem + wave * 576;  // 16 rows x 36 stride
#pragma unroll
  for (int i = 0; i < 4; ++i) {
#pragma unroll
    for (int j = 0; j < 2; ++j) {
      const float bb = bias[bn + wn + j * 16 + l15];
#pragma unroll
      for (int r = 0; r < 4; ++r)
        T[(quad * 4 + r) * 36 + j * 16 + l15] = acc[i][j][r] + bb;
    }
#pragma unroll
    for (int c = 0; c < 2; ++c) {
      const int row = (lane >> 3) + 8 * c;
      f32x4 v = *(const f32x4*)(T + row * 36 + (lane & 7) * 4);
      *(f32x4*)(Out + (size_t)(bm + wm + i * 16 + row) * N + bn + wn +
                (lane & 7) * 4) = v;
    }
  }
}

extern "C" void kernel_launch(void* const* d_in, const int* in_sizes, int n_in,
                              void* d_out, int out_size, void* d_ws,
                              size_t ws_size, hipStream_t stream) {
  // setup_inputs order: x, encoder_x, Wq, bq, Wk, bk, Wv, bv, Wo, bo
  const float* x  = (const float*)d_in[0];
  const float* Wv = (const float*)d_in[6];
  const float* bv = (const float*)d_in[7];
  const float* Wo = (const float*)d_in[8];
  const float* bo = (const float*)d_in[9];
  float* out = (float*)d_out;

  constexpr int L = 2048, D = 1024, NO = 1024;  // NO = H*QKV
  constexpr int M = 4 * L;                      // B*L = 8192

  char* ws = (char*)d_ws;
  short* x_bf   = (short*)(ws);                 // 16 MB: x as bf16
  short* wot_bf = (short*)(ws + (16u << 20));   //  2 MB: Wo^T bf16
  short* wt_bf  = (short*)(ws + (18u << 20));   //  2 MB: 2048*(Wv@Wo)^T bf16
  float* biasc  = (float*)(ws + (20u << 20));   //  4 KB: fused bias

  prep<<<4416, 256, 0, stream>>>(x, x_bf, Wo, wot_bf, bv, bo, biasc);
  gemm_w<<<dim3(16, 32), 256, 0, stream>>>(wot_bf, Wv, wt_bf, NO, D);
  gemm_main<<<(M / 128) * (NO / 64), 256, 0, stream>>>(
      x_bf, wt_bf, biasc, out, M, NO, D);
}

// Round 2
// 177.340 us; speedup vs baseline: 1.0205x; 1.0205x over previous
//
#include <hip/hip_runtime.h>
#include <stdint.h>

// ---------------------------------------------------------------------------
// CrossAttention_43061342110469 — algebraic reduction:
// einsum('bvhd,bhqk->bvhd', v, softmax(scores)) == v * L  (softmax rows sum
// to 1; summed over q gives L=2048). So out = 2048*(x @ Wv @ Wo) + const.
//
// R1 restructure:
//   K1 prep_w   : transpose-cast Wo + fused bias        (320 blocks, ~3 us)
//   K2 mid      : gemm_w blocks [0,512) + x-cast [512,4608) — independent
//                 ranges; memory-bound cast overlaps latency-bound gemm_w.
//   K3 gemm_main: 128x128 m97 structure (32 MFMA/K-step/wave), 512 blocks,
//                 XCD-aware order, XOR-swizzled LDS, LDS-staged epilogue.
// ---------------------------------------------------------------------------

typedef __attribute__((ext_vector_type(8))) short bf16x8;
typedef __attribute__((ext_vector_type(4))) float f32x4;

typedef __attribute__((address_space(1))) void as1_void;
typedef __attribute__((address_space(3))) void as3_void;
#define GLD16(g, s)                                                          \
  __builtin_amdgcn_global_load_lds((as1_void*)(g), (as3_void*)(s), 16, 0, 0)

__device__ __forceinline__ short f2bf(float f) {
  union { float f; uint32_t u; } v; v.f = f;
  uint32_t r = v.u + 0x7FFFu + ((v.u >> 16) & 1u);  // round-to-nearest-even
  return (short)(r >> 16);
}

// pack 8 fp32 -> bf16x8 (+0x8000, take high16 via v_perm)
__device__ __forceinline__ bf16x8 pack8(f32x4 a, f32x4 b) {
  union { f32x4 f; uint32_t u[4]; } x, y;
  x.f = a; y.f = b;
#pragma unroll
  for (int t = 0; t < 4; ++t) x.u[t] += 0x8000u;
#pragma unroll
  for (int t = 0; t < 4; ++t) y.u[t] += 0x8000u;
  union { bf16x8 v; uint32_t u[4]; } o;
  o.u[0] = __builtin_amdgcn_perm(x.u[1], x.u[0], 0x07060302);
  o.u[1] = __builtin_amdgcn_perm(x.u[3], x.u[2], 0x07060302);
  o.u[2] = __builtin_amdgcn_perm(y.u[1], y.u[0], 0x07060302);
  o.u[3] = __builtin_amdgcn_perm(y.u[3], y.u[2], 0x07060302);
  return o.v;
}

// ---- K1: blocks [0,256) transpose-cast Wo; [256,320) fused bias -----------
__global__ __launch_bounds__(256) void prep_w(
    const float* __restrict__ Wo, short* __restrict__ wot,
    const float* __restrict__ bv, const float* __restrict__ bo,
    float* __restrict__ biasc) {
  constexpr int N = 1024, D = 1024;
  __shared__ union {
    float tile[64][65];
    float red[256];
  } sm;
  const int b = blockIdx.x, tid = threadIdx.x;

  if (b < 256) {  // ---- transpose-cast Wo (64x64 tiles via LDS)
    const int br = (b >> 4) * 64, bc = (b & 15) * 64;
#pragma unroll
    for (int t = 0; t < 16; ++t) {
      int idx = t * 256 + tid;
      int r = idx >> 6, c = idx & 63;
      sm.tile[r][c] = Wo[(size_t)(br + r) * N + bc + c];
    }
    __syncthreads();
#pragma unroll
    for (int t = 0; t < 16; ++t) {
      int idx = t * 256 + tid;
      int r = idx >> 6, c = idx & 63;
      wot[(size_t)(bc + r) * N + br + c] = f2bf(sm.tile[c][r]);
    }
  } else {  // ---- bias_c[n] = 2048 * sum_k bv[k]*Wo[k,n] + bo[n]
    const int b3 = b - 256;
    const int nx = tid & 15, ky = tid >> 4;
    const int n = b3 * 16 + nx;
    float s = 0.f;
    for (int k = ky; k < D; k += 16)
      s += bv[k] * Wo[(size_t)k * N + n];
    sm.red[tid] = s;
    __syncthreads();
#pragma unroll
    for (int st = 128; st >= 16; st >>= 1) {
      if (tid < st) sm.red[tid] += sm.red[tid + st];
      __syncthreads();
    }
    if (ky == 0) biasc[n] = 2048.0f * sm.red[nx] + bo[n];
  }
}

// ---- K2: blocks [0,512) gemm_w (Wt = 2048*(Wv@Wo)^T, 32x64 tiles);
//          blocks [512,4608) cast x fp32->bf16. Independent ranges, so the
//          memory-bound cast co-schedules with the latency-bound gemm. ------
__global__ __launch_bounds__(256) void mid(
    const float* __restrict__ x, short* __restrict__ x_bf,
    const short* __restrict__ Wot, const float* __restrict__ Wv,
    short* __restrict__ Wt) {
  constexpr int BK = 64, N = 1024, K = 1024;
  __shared__ __align__(16) short As[32 * BK];   //  4 KB bf16
  __shared__ __align__(16) float Bsf[64 * BK];  // 16 KB fp32
  const int b = blockIdx.x, tid = threadIdx.x;

  if (b >= 512) {  // ---- cast x: fp32 -> bf16, 8 elems/thread
    const int i = (b - 512) * 256 + tid;
    const float4* p = (const float4*)x;
    float4 a = p[2 * (size_t)i], c = p[2 * (size_t)i + 1];
    bf16x8 o;
    o[0] = f2bf(a.x); o[1] = f2bf(a.y); o[2] = f2bf(a.z); o[3] = f2bf(a.w);
    o[4] = f2bf(c.x); o[5] = f2bf(c.y); o[6] = f2bf(c.z); o[7] = f2bf(c.w);
    *(bf16x8*)(x_bf + 8 * (size_t)i) = o;
    return;
  }

  // ---- gemm_w: 32x64 tiles, BK=64, 512 blocks = 2/CU. 4 waves, each 16x32.
  const int lane = tid & 63, wave = tid >> 6;
  const int bm = (b >> 4) * 32, bn = (b & 15) * 64;
  const int wm = (wave & 1) * 16, wn = (wave >> 1) * 32;
  const int l15 = lane & 15, quad = lane >> 4;

  f32x4 acc[2];
  acc[0] = (f32x4){0.f, 0.f, 0.f, 0.f};
  acc[1] = (f32x4){0.f, 0.f, 0.f, 0.f};

  // A: 32 rows x 8 chunks(16B) = 256 chunks, 1/thread, XOR swizzle
  const int ar = tid >> 3, ac8 = (tid & 7) ^ (ar & 7);
  const short* pa = Wot + (size_t)(bm + ar) * K + ac8 * 8;
  short* la = As + tid * 8;
  // B (fp32): 64 rows x 16 chunks(16B) = 1024 chunks, 4/thread
  const int br = tid >> 4, bc4 = (tid & 15) ^ (br & 7);
  const float* pb = Wv + (size_t)(bn + br) * K + bc4 * 4;
  float* lb = Bsf + tid * 4;

  for (int kt = 0; kt < K; kt += BK) {
    GLD16(pa, la);
#pragma unroll
    for (int s = 0; s < 4; ++s) GLD16(pb + (size_t)(16 * s) * K, lb + 1024 * s);
    pa += BK; pb += BK;
    __syncthreads();
#pragma unroll
    for (int kk = 0; kk < 2; ++kk) {
      const int r = wm + l15;
      bf16x8 af =
          *(const bf16x8*)(As + r * BK + ((kk * 4 + quad) ^ (r & 7)) * 8);
#pragma unroll
      for (int j = 0; j < 2; ++j) {
        const int rn = wn + j * 16 + l15;
        const int c4 = kk * 8 + quad * 2;
        f32x4 u0 = *(const f32x4*)(Bsf + (rn * 16 + (c4 ^ (rn & 7))) * 4);
        f32x4 u1 = *(const f32x4*)(Bsf + (rn * 16 + ((c4 + 1) ^ (rn & 7))) * 4);
        acc[j] = __builtin_amdgcn_mfma_f32_16x16x32_bf16(af, pack8(u0, u1),
                                                         acc[j], 0, 0, 0);
      }
    }
    __syncthreads();
  }
#pragma unroll
  for (int j = 0; j < 2; ++j) {
    const int col = bn + wn + j * 16 + l15;
    const int row0 = bm + wm + quad * 4;
#pragma unroll
    for (int r = 0; r < 4; ++r)
      Wt[(size_t)(row0 + r) * N + col] = f2bf(2048.f * acc[j][r]);
  }
}

// ---- K3: out = x_bf @ Wt^T + bias; 128x128 tile (m97 structure) -----------
// grid 512 = 64 M-tiles x 8 N-tiles; bm = b&63 so the 8 N-tiles of one
// A-tile all land on XCD (b%8) -> A-tile L2-resident (2MB A + 2MB B / XCD).
// Per K-step/wave: 8 ds_read_b128 + 32 MFMA (m97 ratio, verified ~900 TF).
__global__ __launch_bounds__(256) void gemm_main(
    const short* __restrict__ A, const short* __restrict__ Bt,
    const float* __restrict__ bias, float* __restrict__ Out,
    int M, int N, int K) {
  constexpr int BK = 64;
  __shared__ __align__(16) char smem[32768];  // As 16K + Bs 16K; epilogue T
  short* As = (short*)smem;
  short* Bs = (short*)(smem + 16384);
  const int tid = threadIdx.x, lane = tid & 63, wave = tid >> 6;
  const int b = blockIdx.x;
  const int bm = (b & 63) * 128;
  const int bn = (b >> 6) * 128;
  const int wm = (wave & 1) * 64, wn = (wave >> 1) * 64;
  const int l15 = lane & 15, quad = lane >> 4;

  f32x4 acc[4][4];
#pragma unroll
  for (int i = 0; i < 4; ++i)
#pragma unroll
    for (int j = 0; j < 4; ++j) acc[i][j] = (f32x4){0.f, 0.f, 0.f, 0.f};

  // staging with XOR chunk swizzle (LDS[row][c8] = global [row][c8^(row&7)])
  const int srow = tid >> 3, sc8 = (tid & 7) ^ (srow & 7);
  const short* pa = A + (size_t)(bm + srow) * K + sc8 * 8;
  const short* pb = Bt + (size_t)(bn + srow) * K + sc8 * 8;
  short* la = As + tid * 8;
  short* lb = Bs + tid * 8;

  for (int kt = 0; kt < K; kt += BK) {
#pragma unroll
    for (int s = 0; s < 4; ++s) GLD16(pa + (size_t)(32 * s) * K, la + 2048 * s);
#pragma unroll
    for (int s = 0; s < 4; ++s) GLD16(pb + (size_t)(32 * s) * K, lb + 2048 * s);
    pa += BK; pb += BK;
    __syncthreads();
#pragma unroll
    for (int kk = 0; kk < 2; ++kk) {
      bf16x8 af[4], bfr[4];
#pragma unroll
      for (int i = 0; i < 4; ++i) {
        const int r = wm + i * 16 + l15;
        af[i] = *(const bf16x8*)(As + r * BK + ((kk * 4 + quad) ^ (r & 7)) * 8);
      }
#pragma unroll
      for (int j = 0; j < 4; ++j) {
        const int r = wn + j * 16 + l15;
        bfr[j] = *(const bf16x8*)(Bs + r * BK + ((kk * 4 + quad) ^ (r & 7)) * 8);
      }
#pragma unroll
      for (int i = 0; i < 4; ++i)
#pragma unroll
        for (int j = 0; j < 4; ++j)
          acc[i][j] = __builtin_amdgcn_mfma_f32_16x16x32_bf16(
              af[i], bfr[j], acc[i][j], 0, 0, 0);
    }
    __syncthreads();
  }

  // epilogue: MFMA C layout (col=l15, row=quad*4+r) -> per-wave LDS tile
  // (16 x 64, stride 68) -> full-line float4 stores. Same-wave ordering only.
  float* T = (float*)smem + wave * 1088;  // 16 rows x 68 stride
#pragma unroll
  for (int i = 0; i < 4; ++i) {
#pragma unroll
    for (int j = 0; j < 4; ++j) {
      const float bb = bias[bn + wn + j * 16 + l15];
#pragma unroll
      for (int r = 0; r < 4; ++r)
        T[(quad * 4 + r) * 68 + j * 16 + l15] = acc[i][j][r] + bb;
    }
#pragma unroll
    for (int p = 0; p < 4; ++p) {
      const int row = (lane >> 4) + 4 * p;
      const int ch = lane & 15;
      f32x4 v = *(const f32x4*)(T + row * 68 + ch * 4);
      *(f32x4*)(Out + (size_t)(bm + wm + i * 16 + row) * N + bn + wn +
                ch * 4) = v;
    }
  }
}

extern "C" void kernel_launch(void* const* d_in, const int* in_sizes, int n_in,
                              void* d_out, int out_size, void* d_ws,
                              size_t ws_size, hipStream_t stream) {
  // setup_inputs order: x, encoder_x, Wq, bq, Wk, bk, Wv, bv, Wo, bo
  const float* x  = (const float*)d_in[0];
  const float* Wv = (const float*)d_in[6];
  const float* bv = (const float*)d_in[7];
  const float* Wo = (const float*)d_in[8];
  const float* bo = (const float*)d_in[9];
  float* out = (float*)d_out;

  constexpr int L = 2048, D = 1024, NO = 1024;  // NO = H*QKV
  constexpr int M = 4 * L;                      // B*L = 8192

  char* ws = (char*)d_ws;
  short* x_bf   = (short*)(ws);                 // 16 MB: x as bf16
  short* wot_bf = (short*)(ws + (16u << 20));   //  2 MB: Wo^T bf16
  short* wt_bf  = (short*)(ws + (18u << 20));   //  2 MB: 2048*(Wv@Wo)^T bf16
  float* biasc  = (float*)(ws + (20u << 20));   //  4 KB: fused bias

  prep_w<<<320, 256, 0, stream>>>(Wo, wot_bf, bv, bo, biasc);
  mid<<<4608, 256, 0, stream>>>(x, x_bf, wot_bf, Wv, wt_bf);
  gemm_main<<<(M / 128) * (NO / 128), 256, 0, stream>>>(
      x_bf, wt_bf, biasc, out, M, NO, D);
}

// Round 4
// 165.286 us; speedup vs baseline: 1.0949x; 1.0729x over previous
//
#include <hip/hip_runtime.h>
#include <stdint.h>

// ---------------------------------------------------------------------------
// CrossAttention_43061342110469 — algebraic reduction:
// einsum('bvhd,bhqk->bvhd', v, softmax(scores)) == v * L  (softmax rows sum
// to 1; summed over q gives L=2048). So out = 2048*(x @ Wv @ Wo) + const.
//
// R3 (resubmitted unchanged after container failure): 2 launches.
//   K1 wgemm    : blocks [0,512) Wt[n,k] = 2048*sum_j Wo[j,n]*Wv[k,j] with
//                 in-kernel LDS transpose of Wo (no wot intermediate);
//                 blocks [512,576) fused bias biasc[n].
//   K2 gemm_main: out = x @ Wt^T + biasc. A-staging fuses fp32->bf16 cast
//                 (reg-stage + pack8 + ds_write), killing the 32 MB x_bf
//                 round-trip and the whole cast kernel. B via GLD16.
// ---------------------------------------------------------------------------

typedef __attribute__((ext_vector_type(8))) short bf16x8;
typedef __attribute__((ext_vector_type(4))) float f32x4;

typedef __attribute__((address_space(1))) void as1_void;
typedef __attribute__((address_space(3))) void as3_void;
#define GLD16(g, s)                                                          \
  __builtin_amdgcn_global_load_lds((as1_void*)(g), (as3_void*)(s), 16, 0, 0)

__device__ __forceinline__ short f2bf(float f) {
  union { float f; uint32_t u; } v; v.f = f;
  uint32_t r = v.u + 0x7FFFu + ((v.u >> 16) & 1u);  // round-to-nearest-even
  return (short)(r >> 16);
}

// pack 8 fp32 -> bf16x8 (+0x8000, take high16 via v_perm)
__device__ __forceinline__ bf16x8 pack8(f32x4 a, f32x4 b) {
  union { f32x4 f; uint32_t u[4]; } x, y;
  x.f = a; y.f = b;
#pragma unroll
  for (int t = 0; t < 4; ++t) x.u[t] += 0x8000u;
#pragma unroll
  for (int t = 0; t < 4; ++t) y.u[t] += 0x8000u;
  union { bf16x8 v; uint32_t u[4]; } o;
  o.u[0] = __builtin_amdgcn_perm(x.u[1], x.u[0], 0x07060302);
  o.u[1] = __builtin_amdgcn_perm(x.u[3], x.u[2], 0x07060302);
  o.u[2] = __builtin_amdgcn_perm(y.u[1], y.u[0], 0x07060302);
  o.u[3] = __builtin_amdgcn_perm(y.u[3], y.u[2], 0x07060302);
  return o.v;
}

// ---- K1: blocks [0,512): Wt = 2048*(Wv@Wo)^T with in-kernel Wo transpose;
//          blocks [512,576): biasc[n] = 2048*sum_k bv[k]*Wo[k,n] + bo[n].
// Gemm tile: 32 n-rows x 64 k-cols, BK=64 over j. 512 blocks = 2/CU.
// A-frag (Wo^T rows) read from a padded fp32 LDS tile column-wise (scalar
// ds_read_b32 x8 + pack8; ~4-way bank conflict, fine for a 2.1 GFLOP side
// kernel). B (Wv) staged fp32 via GLD16 with XOR swizzle (verified R2 path).
__global__ __launch_bounds__(256) void wgemm(
    const float* __restrict__ Wo, const float* __restrict__ Wv,
    const float* __restrict__ bv, const float* __restrict__ bo,
    short* __restrict__ Wt, float* __restrict__ biasc) {
  constexpr int BK = 64, NW = 1024;  // NW = row stride of Wo / Wv / Wt
  __shared__ __align__(16) float Bsf[64 * BK];  // 16 KB fp32 (Wv tile)
  __shared__ __align__(16) float Ts[64 * 36];   //  9 KB fp32 (Wo^T stage)
  const int b = blockIdx.x, tid = threadIdx.x;

  if (b >= 512) {  // ---- bias blocks
    float* red = Bsf;
    const int b3 = b - 512;
    const int nx = tid & 15, ky = tid >> 4;
    const int n = b3 * 16 + nx;
    float s = 0.f;
    for (int k = ky; k < 1024; k += 16)
      s += bv[k] * Wo[(size_t)k * NW + n];
    red[tid] = s;
    __syncthreads();
#pragma unroll
    for (int st = 128; st >= 16; st >>= 1) {
      if (tid < st) red[tid] += red[tid + st];
      __syncthreads();
    }
    if (ky == 0) biasc[n] = 2048.0f * red[nx] + bo[n];
    return;
  }

  // ---- gemm blocks: bm = n-tile (Wo cols), bn = k-tile (Wv rows)
  const int lane = tid & 63, wave = tid >> 6;
  const int bm = (b >> 4) * 32, bn = (b & 15) * 64;
  const int wm = (wave & 1) * 16, wn = (wave >> 1) * 32;
  const int l15 = lane & 15, quad = lane >> 4;

  f32x4 acc[2];
  acc[0] = (f32x4){0.f, 0.f, 0.f, 0.f};
  acc[1] = (f32x4){0.f, 0.f, 0.f, 0.f};

  // B (fp32): 64 rows x 16 chunks(16B) = 1024 chunks, 4/thread, XOR swizzle
  const int br = tid >> 4, bc4 = (tid & 15) ^ (br & 7);
  const float* pb = Wv + (size_t)(bn + br) * NW + bc4 * 4;
  float* lb = Bsf + tid * 4;

  // A (Wo transpose-stage): rows j = tid>>3 (+32), cols bm + (tid&7)*4
  const int ajr = tid >> 3, ac4 = (tid & 7) * 4;
  const float* pa = Wo + (size_t)ajr * NW + bm + ac4;

  for (int kt = 0; kt < 1024; kt += BK) {
    float4 va = *(const float4*)(pa);
    float4 vb = *(const float4*)(pa + 32 * (size_t)NW);
    pa += (size_t)BK * NW;
#pragma unroll
    for (int s = 0; s < 4; ++s) GLD16(pb + (size_t)(16 * s) * NW, lb + 1024 * s);
    pb += BK;
    *(float4*)(Ts + ajr * 36 + ac4) = va;
    *(float4*)(Ts + (ajr + 32) * 36 + ac4) = vb;
    __syncthreads();
#pragma unroll
    for (int kk = 0; kk < 2; ++kk) {
      // A-frag: n-row = wm+l15, j = (kk*4+quad)*8 + e  (column read of Ts)
      const float* tsp = Ts + ((kk * 4 + quad) * 8) * 36 + wm + l15;
      float av[8];
#pragma unroll
      for (int e = 0; e < 8; ++e) av[e] = tsp[e * 36];
      bf16x8 af = pack8((f32x4){av[0], av[1], av[2], av[3]},
                        (f32x4){av[4], av[5], av[6], av[7]});
#pragma unroll
      for (int j = 0; j < 2; ++j) {
        const int rn = wn + j * 16 + l15;
        const int c4 = kk * 8 + quad * 2;
        f32x4 u0 = *(const f32x4*)(Bsf + (rn * 16 + (c4 ^ (rn & 7))) * 4);
        f32x4 u1 = *(const f32x4*)(Bsf + (rn * 16 + ((c4 + 1) ^ (rn & 7))) * 4);
        acc[j] = __builtin_amdgcn_mfma_f32_16x16x32_bf16(af, pack8(u0, u1),
                                                         acc[j], 0, 0, 0);
      }
    }
    __syncthreads();
  }
#pragma unroll
  for (int j = 0; j < 2; ++j) {
    const int col = bn + wn + j * 16 + l15;   // k-dim
    const int row0 = bm + wm + quad * 4;      // n-dim
#pragma unroll
    for (int r = 0; r < 4; ++r)
      Wt[(size_t)(row0 + r) * NW + col] = f2bf(2048.f * acc[j][r]);
  }
}

// ---- K2: out = x @ Wt^T + biasc; 128x128 tile, fused fp32->bf16 A-cast ----
// grid 512 = 64 M-tiles x 8 N-tiles; bm = b&63 so the 8 N-tiles of one
// A-panel share XCD (b%8) -> x panel L2-resident, x read ~once from HBM.
// A: 8 float4 loads + 4 pack8 + 4 ds_write_b128 per thread per K-step
// (XOR chunk swizzle preserved). B: 4x GLD16. 32 MFMA/K-step/wave.
__global__ __launch_bounds__(256) void gemm_main(
    const float* __restrict__ X, const short* __restrict__ Bt,
    const float* __restrict__ bias, float* __restrict__ Out,
    int M, int N, int K) {
  constexpr int BK = 64;
  __shared__ __align__(16) char smem[32768];  // As 16K + Bs 16K; epilogue T
  short* As = (short*)smem;
  short* Bs = (short*)(smem + 16384);
  const int tid = threadIdx.x, lane = tid & 63, wave = tid >> 6;
  const int b = blockIdx.x;
  const int bm = (b & 63) * 128;
  const int bn = (b >> 6) * 128;
  const int wm = (wave & 1) * 64, wn = (wave >> 1) * 64;
  const int l15 = lane & 15, quad = lane >> 4;

  f32x4 acc[4][4];
#pragma unroll
  for (int i = 0; i < 4; ++i)
#pragma unroll
    for (int j = 0; j < 4; ++j) acc[i][j] = (f32x4){0.f, 0.f, 0.f, 0.f};

  // staging with XOR chunk swizzle (LDS[row][c8] = global [row][c8^(row&7)])
  const int srow = tid >> 3, sc8 = (tid & 7) ^ (srow & 7);
  const float* pa = X + (size_t)(bm + srow) * K + sc8 * 8;  // fp32! 8 floats
  const short* pb = Bt + (size_t)(bn + srow) * K + sc8 * 8;
  short* la = As + tid * 8;
  short* lb = Bs + tid * 8;

  for (int kt = 0; kt < K; kt += BK) {
    float4 a0[4], a1[4];
#pragma unroll
    for (int s = 0; s < 4; ++s) {
      const float* p = pa + (size_t)(32 * s) * K;
      a0[s] = *(const float4*)(p);
      a1[s] = *(const float4*)(p + 4);
    }
#pragma unroll
    for (int s = 0; s < 4; ++s) GLD16(pb + (size_t)(32 * s) * K, lb + 2048 * s);
    pa += BK; pb += BK;
#pragma unroll
    for (int s = 0; s < 4; ++s) {
      *(bf16x8*)(la + 2048 * s) =
          pack8((f32x4){a0[s].x, a0[s].y, a0[s].z, a0[s].w},
                (f32x4){a1[s].x, a1[s].y, a1[s].z, a1[s].w});
    }
    __syncthreads();
#pragma unroll
    for (int kk = 0; kk < 2; ++kk) {
      bf16x8 af[4], bfr[4];
#pragma unroll
      for (int i = 0; i < 4; ++i) {
        const int r = wm + i * 16 + l15;
        af[i] = *(const bf16x8*)(As + r * BK + ((kk * 4 + quad) ^ (r & 7)) * 8);
      }
#pragma unroll
      for (int j = 0; j < 4; ++j) {
        const int r = wn + j * 16 + l15;
        bfr[j] = *(const bf16x8*)(Bs + r * BK + ((kk * 4 + quad) ^ (r & 7)) * 8);
      }
#pragma unroll
      for (int i = 0; i < 4; ++i)
#pragma unroll
        for (int j = 0; j < 4; ++j)
          acc[i][j] = __builtin_amdgcn_mfma_f32_16x16x32_bf16(
              af[i], bfr[j], acc[i][j], 0, 0, 0);
    }
    __syncthreads();
  }

  // epilogue: MFMA C layout (col=l15, row=quad*4+r) -> per-wave LDS tile
  // (16 x 64, stride 68) -> full-line float4 stores. Same-wave ordering only.
  float* T = (float*)smem + wave * 1088;  // 16 rows x 68 stride
#pragma unroll
  for (int i = 0; i < 4; ++i) {
#pragma unroll
    for (int j = 0; j < 4; ++j) {
      const float bb = bias[bn + wn + j * 16 + l15];
#pragma unroll
      for (int r = 0; r < 4; ++r)
        T[(quad * 4 + r) * 68 + j * 16 + l15] = acc[i][j][r] + bb;
    }
#pragma unroll
    for (int p = 0; p < 4; ++p) {
      const int row = (lane >> 4) + 4 * p;
      const int ch = lane & 15;
      f32x4 v = *(const f32x4*)(T + row * 68 + ch * 4);
      *(f32x4*)(Out + (size_t)(bm + wm + i * 16 + row) * N + bn + wn +
                ch * 4) = v;
    }
  }
}

extern "C" void kernel_launch(void* const* d_in, const int* in_sizes, int n_in,
                              void* d_out, int out_size, void* d_ws,
                              size_t ws_size, hipStream_t stream) {
  // setup_inputs order: x, encoder_x, Wq, bq, Wk, bk, Wv, bv, Wo, bo
  const float* x  = (const float*)d_in[0];
  const float* Wv = (const float*)d_in[6];
  const float* bv = (const float*)d_in[7];
  const float* Wo = (const float*)d_in[8];
  const float* bo = (const float*)d_in[9];
  float* out = (float*)d_out;

  constexpr int D = 1024, NO = 1024;  // NO = H*QKV
  constexpr int M = 8192;             // B*L

  char* ws = (char*)d_ws;
  short* wt_bf = (short*)(ws);              // 2 MB: 2048*(Wv@Wo)^T bf16
  float* biasc = (float*)(ws + (2u << 20)); // 4 KB: fused bias

  wgemm<<<576, 256, 0, stream>>>(Wo, Wv, bv, bo, wt_bf, biasc);
  gemm_main<<<(M / 128) * (NO / 128), 256, 0, stream>>>(
      x, wt_bf, biasc, out, M, NO, D);
}